// Round 1
// baseline (390.722 us; speedup 1.0000x reference)
//
#include <hip/hip_runtime.h>
#include <cstdint>
#include <cmath>

// MultiHead attention fused pipeline for MI355X (gfx950).
// B=4, T=2048, E=1024, H=16, hs=64. fp32 in/out, bf16 MFMA compute.

typedef __attribute__((ext_vector_type(8))) __bf16 bf16x8;
typedef __attribute__((ext_vector_type(4))) __bf16 bf16x4;
typedef __attribute__((ext_vector_type(4))) float f32x4;

#define B_ 4
#define T_ 2048
#define E_ 1024
#define H_ 16
#define HS_ 64
#define M_ (B_ * T_)  // 8192

__device__ __forceinline__ f32x4 mfma16(bf16x8 a, bf16x8 b, f32x4 c) {
  return __builtin_amdgcn_mfma_f32_16x16x32_bf16(a, b, c, 0, 0, 0);
}

__device__ __forceinline__ void gload_lds16(const void* g, void* l) {
  __builtin_amdgcn_global_load_lds(
      (const __attribute__((address_space(1))) unsigned int*)g,
      (__attribute__((address_space(3))) unsigned int*)l,
      16, 0, 0);
}

// ---- convert x (fp32) -> Xb (bf16), coalesced, 4 elems/thread ----
__global__ __launch_bounds__(256) void cvt_x_kernel(const float* __restrict__ x,
                                                    __bf16* __restrict__ xb) {
  int i = (blockIdx.x * 256 + threadIdx.x) * 4;
  float4 v = *(const float4*)(x + i);
  bf16x4 o;
  o[0] = (__bf16)v.x; o[1] = (__bf16)v.y; o[2] = (__bf16)v.z; o[3] = (__bf16)v.w;
  *(bf16x4*)(xb + i) = o;
}

// ---- convert W[h][e][d] (fp32) -> Wt[qkv][n=h*64+d][e] (bf16, B^T layout) ----
__global__ __launch_bounds__(256) void cvt_w_kernel(const float* __restrict__ Wq,
                                                    const float* __restrict__ Wk,
                                                    const float* __restrict__ Wv,
                                                    __bf16* __restrict__ wt) {
  int i = blockIdx.x * 256 + threadIdx.x;  // 0 .. 3*1024*1024-1
  int qkv = i >> 20;
  int rem = i & 1048575;
  int n = rem >> 10, e = rem & 1023;
  const float* W = (qkv == 0) ? Wq : (qkv == 1) ? Wk : Wv;
  int h = n >> 6, d = n & 63;
  wt[i] = (__bf16)W[(((size_t)h << 10) + e) * 64 + d];
}

// ---- QKV projection GEMM, m97 conventions: A[M][K] row-major, B^T[N][K],
//      D row=(lane>>4)*4+reg, col=lane&15. 128x128 tile, BK=32, 4 waves. ----
__global__ __launch_bounds__(256) void qkv_gemm_kernel(
    const __bf16* __restrict__ Xb, const __bf16* __restrict__ Wt,
    __bf16* __restrict__ Qb, __bf16* __restrict__ Kb, __bf16* __restrict__ Vt) {
  __shared__ __bf16 As[128 * 32];
  __shared__ __bf16 Bs[128 * 32];
  const int qkv = blockIdx.z;
  const int m0 = blockIdx.x * 128;
  const int n0 = blockIdx.y * 128;
  const int t = threadIdx.x;
  const int lane = t & 63;
  const int w = t >> 6, wr = w >> 1, wc = w & 1;
  const int g = lane >> 4, c = lane & 15;

  const __bf16* wsrc = Wt + ((size_t)qkv << 20);
  f32x4 acc[4][4] = {};

  const __bf16* ga0 = Xb + (size_t)(m0 + (t >> 2)) * 1024 + (t & 3) * 8;
  const __bf16* ga1 = Xb + (size_t)(m0 + 64 + (t >> 2)) * 1024 + (t & 3) * 8;
  const __bf16* gb0 = wsrc + (size_t)(n0 + (t >> 2)) * 1024 + (t & 3) * 8;
  const __bf16* gb1 = wsrc + (size_t)(n0 + 64 + (t >> 2)) * 1024 + (t & 3) * 8;

  for (int k0 = 0; k0 < 1024; k0 += 32) {
    __syncthreads();  // prior compute done before overwrite
    gload_lds16(ga0 + k0, &As[t * 8]);
    gload_lds16(ga1 + k0, &As[2048 + t * 8]);
    gload_lds16(gb0 + k0, &Bs[t * 8]);
    gload_lds16(gb1 + k0, &Bs[2048 + t * 8]);
    __syncthreads();  // compiler drains vmcnt before s_barrier

    bf16x8 af[4], bfr[4];
#pragma unroll
    for (int mi = 0; mi < 4; ++mi)
      af[mi] = *(const bf16x8*)&As[(wr * 64 + mi * 16 + c) * 32 + g * 8];
#pragma unroll
    for (int ni = 0; ni < 4; ++ni)
      bfr[ni] = *(const bf16x8*)&Bs[(wc * 64 + ni * 16 + c) * 32 + g * 8];
#pragma unroll
    for (int mi = 0; mi < 4; ++mi)
#pragma unroll
      for (int ni = 0; ni < 4; ++ni)
        acc[mi][ni] = mfma16(af[mi], bfr[ni], acc[mi][ni]);
  }

  const int mbase = m0 + wr * 64 + g * 4;
  const int nbase = n0 + wc * 64 + c;
  if (qkv < 2) {
    __bf16* dst = (qkv == 0) ? Qb : Kb;  // [B][H][T][64]
#pragma unroll
    for (int mi = 0; mi < 4; ++mi) {
#pragma unroll
      for (int ni = 0; ni < 4; ++ni) {
        int n = nbase + ni * 16;
        int h = n >> 6, d = n & 63;
#pragma unroll
        for (int r = 0; r < 4; ++r) {
          int m = mbase + mi * 16 + r;
          int b = m >> 11, tt = m & 2047;
          dst[(((size_t)b * H_ + h) * T_ + tt) * HS_ + d] = (__bf16)acc[mi][ni][r];
        }
      }
    }
  } else {
    // V stored transposed: Vt[B][H][d][t]  (lane's 4 acc rows are 4 contiguous t)
#pragma unroll
    for (int mi = 0; mi < 4; ++mi) {
      int m = mbase + mi * 16;
      int b = m >> 11, tt = m & 2047;
#pragma unroll
      for (int ni = 0; ni < 4; ++ni) {
        int n = nbase + ni * 16;
        int h = n >> 6, d = n & 63;
        bf16x4 pk;
        pk[0] = (__bf16)acc[mi][ni][0];
        pk[1] = (__bf16)acc[mi][ni][1];
        pk[2] = (__bf16)acc[mi][ni][2];
        pk[3] = (__bf16)acc[mi][ni][3];
        *(bf16x4*)&Vt[(((size_t)b * H_ + h) * HS_ + d) * T_ + tt] = pk;
      }
    }
  }
}

// ---- fused causal attention: 1 block per (b,h,q-tile of 64 rows) ----
// 4 waves x 16 q-rows. KVBLK=64. Q in regs; K, V^T in LDS (stride 72 pad).
__global__ __launch_bounds__(256) void attn_kernel(
    const __bf16* __restrict__ Qb, const __bf16* __restrict__ Kb,
    const __bf16* __restrict__ Vt, float* __restrict__ out) {
  __shared__ __bf16 Ks[64 * 72];
  __shared__ __bf16 Vs[64 * 72];
  __shared__ __bf16 Ps[64 * 72];

  const int qt = blockIdx.x;  // 0..31
  const int bh = blockIdx.y;  // 0..63
  const int b = bh >> 4, h = bh & 15;
  const int t = threadIdx.x;
  const int lane = t & 63, w = t >> 6, g = lane >> 4, c = lane & 15;
  const int qbase = qt * 64;

  const __bf16* Qg = Qb + ((size_t)bh * T_ + qbase) * HS_;
  const __bf16* Kg = Kb + (size_t)bh * T_ * HS_;
  const __bf16* Vg = Vt + (size_t)bh * HS_ * T_;

  // Q fragments: row = lane&15 within this wave's 16-row stripe, k contiguous
  bf16x8 qf0 = *(const bf16x8*)(Qg + (w * 16 + c) * 64 + g * 8);
  bf16x8 qf1 = *(const bf16x8*)(Qg + (w * 16 + c) * 64 + g * 8 + 32);

  f32x4 oacc[4] = {};
  float mrun[4], lrun[4];
#pragma unroll
  for (int r = 0; r < 4; ++r) { mrun[r] = -INFINITY; lrun[r] = 0.f; }

  for (int kt = 0; kt <= qt; ++kt) {
    const int kbase = kt * 64;
    __syncthreads();  // prev iteration's LDS reads complete
#pragma unroll
    for (int j = 0; j < 2; ++j) {
      int tt = t + j * 256;
      int row = tt >> 3, c8 = (tt & 7) * 8;
      *(uint4*)&Ks[row * 72 + c8] = *(const uint4*)(Kg + (size_t)(kbase + row) * 64 + c8);
      *(uint4*)&Vs[row * 72 + c8] = *(const uint4*)(Vg + (size_t)row * T_ + kbase + c8);
    }
    __syncthreads();

    // S = Q K^T  (S[tq=g*4+r][tk=fj*16+c])
    f32x4 s[4];
#pragma unroll
    for (int fj = 0; fj < 4; ++fj) {
      bf16x8 k0 = *(const bf16x8*)&Ks[(fj * 16 + c) * 72 + g * 8];
      bf16x8 k1 = *(const bf16x8*)&Ks[(fj * 16 + c) * 72 + 32 + g * 8];
      f32x4 z = {0.f, 0.f, 0.f, 0.f};
      z = mfma16(qf0, k0, z);
      z = mfma16(qf1, k1, z);
      s[fj] = z;
    }

    const bool diag = (kt == qt);
#pragma unroll
    for (int fj = 0; fj < 4; ++fj)
#pragma unroll
      for (int r = 0; r < 4; ++r) {
        float v = s[fj][r] * 0.03125f;  // 1/sqrt(E)=1/32
        if (diag && (kbase + fj * 16 + c) > (qbase + w * 16 + g * 4 + r))
          v = -INFINITY;
        s[fj][r] = v;
      }

    // online softmax: row reduce over fj (in-lane) + 16 lanes (shfl_xor 1,2,4,8)
    float fac[4];
#pragma unroll
    for (int r = 0; r < 4; ++r) {
      float mx = fmaxf(fmaxf(s[0][r], s[1][r]), fmaxf(s[2][r], s[3][r]));
      mx = fmaxf(mx, __shfl_xor(mx, 1));
      mx = fmaxf(mx, __shfl_xor(mx, 2));
      mx = fmaxf(mx, __shfl_xor(mx, 4));
      mx = fmaxf(mx, __shfl_xor(mx, 8));
      float mn = fmaxf(mrun[r], mx);
      fac[r] = __expf(mrun[r] - mn);
      float sum = 0.f;
#pragma unroll
      for (int fj = 0; fj < 4; ++fj) {
        float p = __expf(s[fj][r] - mn);
        s[fj][r] = p;
        sum += p;
      }
      sum += __shfl_xor(sum, 1);
      sum += __shfl_xor(sum, 2);
      sum += __shfl_xor(sum, 4);
      sum += __shfl_xor(sum, 8);
      lrun[r] = lrun[r] * fac[r] + sum;
      mrun[r] = mn;
    }
#pragma unroll
    for (int fn = 0; fn < 4; ++fn)
#pragma unroll
      for (int r = 0; r < 4; ++r) oacc[fn][r] *= fac[r];

    // P -> bf16 -> LDS (each wave touches only its own 16-row stripe)
#pragma unroll
    for (int fj = 0; fj < 4; ++fj)
#pragma unroll
      for (int r = 0; r < 4; ++r)
        Ps[(w * 16 + g * 4 + r) * 72 + fj * 16 + c] = (__bf16)s[fj][r];

    // same-wave write->read fence (no cross-wave P dependency)
    asm volatile("s_waitcnt lgkmcnt(0)" ::: "memory");

    // O += P V  (A=P[tq][s], B=V^T[d][s])
#pragma unroll
    for (int ks = 0; ks < 2; ++ks) {
      bf16x8 pf = *(const bf16x8*)&Ps[(w * 16 + c) * 72 + ks * 32 + g * 8];
#pragma unroll
      for (int fn = 0; fn < 4; ++fn) {
        bf16x8 vf = *(const bf16x8*)&Vs[(fn * 16 + c) * 72 + ks * 32 + g * 8];
        oacc[fn] = mfma16(pf, vf, oacc[fn]);
      }
    }
  }

  // epilogue: out[b][t][h*64+d] fp32
#pragma unroll
  for (int fn = 0; fn < 4; ++fn)
#pragma unroll
    for (int r = 0; r < 4; ++r) {
      int tq = qbase + w * 16 + g * 4 + r;
      out[((size_t)b * T_ + tq) * E_ + h * 64 + fn * 16 + c] =
          oacc[fn][r] / lrun[r];
    }
}

extern "C" void kernel_launch(void* const* d_in, const int* in_sizes, int n_in,
                              void* d_out, int out_size, void* d_ws, size_t ws_size,
                              hipStream_t stream) {
  const float* x = (const float*)d_in[0];
  const float* Wq = (const float*)d_in[1];
  const float* Wk = (const float*)d_in[2];
  const float* Wv = (const float*)d_in[3];
  float* out = (float*)d_out;

  // workspace layout (bytes):
  //   Xb  [8192][1024] bf16 : 16 MiB @ 0
  //   Wt  [3][1024][1024]   :  6 MiB @ 16 MiB
  //   Qb  [4][16][2048][64] : 16 MiB @ 22 MiB
  //   Kb                    : 16 MiB @ 38 MiB
  //   Vt  [4][16][64][2048] : 16 MiB @ 54 MiB   (total 70 MiB)
  char* ws = (char*)d_ws;
  __bf16* Xb = (__bf16*)ws;
  __bf16* Wt = (__bf16*)(ws + (16u << 20));
  __bf16* Qb = (__bf16*)(ws + (22u << 20));
  __bf16* Kb = (__bf16*)(ws + (38u << 20));
  __bf16* Vt = (__bf16*)(ws + (54u << 20));

  cvt_x_kernel<<<8192, 256, 0, stream>>>(x, Xb);
  cvt_w_kernel<<<12288, 256, 0, stream>>>(Wq, Wk, Wv, Wt);
  qkv_gemm_kernel<<<dim3(64, 8, 3), 256, 0, stream>>>(Xb, Wt, Qb, Kb, Vt);
  attn_kernel<<<dim3(32, 64), 256, 0, stream>>>(Qb, Kb, Vt, out);
}

// Round 2
// 221.437 us; speedup vs baseline: 1.7645x; 1.7645x over previous
//
#include <hip/hip_runtime.h>
#include <cstdint>
#include <cmath>

// MultiHead attention fused pipeline for MI355X (gfx950).
// B=4, T=2048, E=1024, H=16, hs=64. fp32 in/out, bf16 MFMA compute.
// Round 2: m214-style 8-wave 32x32 attention (swapped QK^T, in-register
// softmax+P via cvt_pk/permlane32_swap, swizzled dbuf K/V LDS, 1 barrier/tile).

typedef __attribute__((ext_vector_type(8))) __bf16 bf16x8;
typedef __attribute__((ext_vector_type(4))) __bf16 bf16x4;
typedef __attribute__((ext_vector_type(4))) float f32x4;
typedef __attribute__((ext_vector_type(16))) float f32x16;

#define B_ 4
#define T_ 2048
#define E_ 1024
#define H_ 16
#define HS_ 64

__device__ __forceinline__ f32x4 mfma16(bf16x8 a, bf16x8 b, f32x4 c) {
  return __builtin_amdgcn_mfma_f32_16x16x32_bf16(a, b, c, 0, 0, 0);
}
__device__ __forceinline__ f32x16 mfma32(bf16x8 a, bf16x8 b, f32x16 c) {
  return __builtin_amdgcn_mfma_f32_32x32x16_bf16(a, b, c, 0, 0, 0);
}

__device__ __forceinline__ void gload_lds16(const void* g, void* l) {
  __builtin_amdgcn_global_load_lds(
      (const __attribute__((address_space(1))) unsigned int*)g,
      (__attribute__((address_space(3))) unsigned int*)l,
      16, 0, 0);
}

__device__ __forceinline__ unsigned cvt_pk_bf16(float lo, float hi) {
  unsigned r;
  asm("v_cvt_pk_bf16_f32 %0, %1, %2" : "=v"(r) : "v"(lo), "v"(hi));
  return r;
}
// v_permlane32_swap_b32 vdst, vsrc: dst.hi <-> src.lo.
// After: a = [a.lo | b.lo], b = [a.hi | b.hi].
__device__ __forceinline__ void pl32swap(unsigned& a, unsigned& b) {
  asm("v_permlane32_swap_b32 %0, %1" : "+v"(a), "+v"(b));
}

// ---- convert x (fp32) -> Xb (bf16), coalesced, 4 elems/thread ----
__global__ __launch_bounds__(256) void cvt_x_kernel(const float* __restrict__ x,
                                                    __bf16* __restrict__ xb) {
  int i = (blockIdx.x * 256 + threadIdx.x) * 4;
  float4 v = *(const float4*)(x + i);
  bf16x4 o;
  o[0] = (__bf16)v.x; o[1] = (__bf16)v.y; o[2] = (__bf16)v.z; o[3] = (__bf16)v.w;
  *(bf16x4*)(xb + i) = o;
}

// ---- W[h][e][d] (fp32) -> Wt[qkv][n=h*64+d][e] (bf16, B^T layout) ----
// LDS tile transpose: coalesced reads (lanes vary d) + coalesced writes (vary e).
__global__ __launch_bounds__(256) void cvt_w_kernel(const float* __restrict__ Wq,
                                                    const float* __restrict__ Wk,
                                                    const float* __restrict__ Wv,
                                                    __bf16* __restrict__ wt) {
  __shared__ float tile[64][65];
  const int e0 = blockIdx.x * 64;      // 16 e-tiles
  const int h = blockIdx.y;            // 16 heads
  const int qkv = blockIdx.z;          // 3
  const int t = threadIdx.x;
  const float* W = (qkv == 0) ? Wq : (qkv == 1) ? Wk : Wv;
#pragma unroll
  for (int j = 0; j < 16; ++j) {
    int idx = j * 256 + t;
    int e = idx >> 6, d = idx & 63;    // lanes vary d -> coalesced read
    tile[d][e] = W[((size_t)(h * 1024 + e0 + e)) * 64 + d];
  }
  __syncthreads();
#pragma unroll
  for (int j = 0; j < 16; ++j) {
    int idx = j * 256 + t;
    int d = idx >> 6, e = idx & 63;    // lanes vary e -> coalesced write
    wt[((size_t)qkv << 20) + (size_t)(h * 64 + d) * 1024 + e0 + e] =
        (__bf16)tile[d][e];
  }
}

// ---- QKV projection GEMM (m97 conventions), unchanged from round 1 ----
__global__ __launch_bounds__(256) void qkv_gemm_kernel(
    const __bf16* __restrict__ Xb, const __bf16* __restrict__ Wt,
    __bf16* __restrict__ Qb, __bf16* __restrict__ Kb, __bf16* __restrict__ Vt) {
  __shared__ __bf16 As[128 * 32];
  __shared__ __bf16 Bs[128 * 32];
  const int qkv = blockIdx.z;
  const int m0 = blockIdx.x * 128;
  const int n0 = blockIdx.y * 128;
  const int t = threadIdx.x;
  const int lane = t & 63;
  const int w = t >> 6, wr = w >> 1, wc = w & 1;
  const int g = lane >> 4, c = lane & 15;

  const __bf16* wsrc = Wt + ((size_t)qkv << 20);
  f32x4 acc[4][4] = {};

  const __bf16* ga0 = Xb + (size_t)(m0 + (t >> 2)) * 1024 + (t & 3) * 8;
  const __bf16* ga1 = Xb + (size_t)(m0 + 64 + (t >> 2)) * 1024 + (t & 3) * 8;
  const __bf16* gb0 = wsrc + (size_t)(n0 + (t >> 2)) * 1024 + (t & 3) * 8;
  const __bf16* gb1 = wsrc + (size_t)(n0 + 64 + (t >> 2)) * 1024 + (t & 3) * 8;

  for (int k0 = 0; k0 < 1024; k0 += 32) {
    __syncthreads();
    gload_lds16(ga0 + k0, &As[t * 8]);
    gload_lds16(ga1 + k0, &As[2048 + t * 8]);
    gload_lds16(gb0 + k0, &Bs[t * 8]);
    gload_lds16(gb1 + k0, &Bs[2048 + t * 8]);
    __syncthreads();

    bf16x8 af[4], bfr[4];
#pragma unroll
    for (int mi = 0; mi < 4; ++mi)
      af[mi] = *(const bf16x8*)&As[(wr * 64 + mi * 16 + c) * 32 + g * 8];
#pragma unroll
    for (int ni = 0; ni < 4; ++ni)
      bfr[ni] = *(const bf16x8*)&Bs[(wc * 64 + ni * 16 + c) * 32 + g * 8];
#pragma unroll
    for (int mi = 0; mi < 4; ++mi)
#pragma unroll
      for (int ni = 0; ni < 4; ++ni)
        acc[mi][ni] = mfma16(af[mi], bfr[ni], acc[mi][ni]);
  }

  const int mbase = m0 + wr * 64 + g * 4;
  const int nbase = n0 + wc * 64 + c;
  if (qkv < 2) {
    __bf16* dst = (qkv == 0) ? Qb : Kb;  // [B][H][T][64]
#pragma unroll
    for (int mi = 0; mi < 4; ++mi) {
#pragma unroll
      for (int ni = 0; ni < 4; ++ni) {
        int n = nbase + ni * 16;
        int h = n >> 6, d = n & 63;
#pragma unroll
        for (int r = 0; r < 4; ++r) {
          int m = mbase + mi * 16 + r;
          int b = m >> 11, tt = m & 2047;
          dst[(((size_t)b * H_ + h) * T_ + tt) * HS_ + d] = (__bf16)acc[mi][ni][r];
        }
      }
    }
  } else {
    // V stored transposed: Vt[B][H][d][t]
#pragma unroll
    for (int mi = 0; mi < 4; ++mi) {
      int m = mbase + mi * 16;
      int b = m >> 11, tt = m & 2047;
#pragma unroll
      for (int ni = 0; ni < 4; ++ni) {
        int n = nbase + ni * 16;
        int h = n >> 6, d = n & 63;
        bf16x4 pk;
        pk[0] = (__bf16)acc[mi][ni][0];
        pk[1] = (__bf16)acc[mi][ni][1];
        pk[2] = (__bf16)acc[mi][ni][2];
        pk[3] = (__bf16)acc[mi][ni][3];
        *(bf16x4*)&Vt[(((size_t)b * H_ + h) * HS_ + d) * T_ + tt] = pk;
      }
    }
  }
}

// ---- fused causal attention, m214 structure ----
// 256 blocks x 512 threads. Block: one (b,h) x q-tile pair {qp, 7-qp} (256 rows
// each). 8 waves x 32 q-rows. KVBLK=64. Swapped QK^T (lane holds P^T column),
// in-register softmax + cvt_pk/permlane32 P, PV as D[d][tq] (A=V^T, B=P).
// K/V^T tiles XOR-swizzled in LDS (pre-swizzled global source), double-buffered.
__global__ __launch_bounds__(512) void attn_kernel(
    const __bf16* __restrict__ Qb, const __bf16* __restrict__ Kb,
    const __bf16* __restrict__ Vt, float* __restrict__ out) {
  __shared__ __bf16 Ks[2][64 * 64];
  __shared__ __bf16 Vs[2][64 * 64];

  const int j = blockIdx.x;                      // XCD-grouped mapping
  const int bh = (j & 7) + 8 * (j >> 5);         // all 4 blocks of a bh -> same XCD
  const int qp = (j >> 3) & 3;
  const int b = bh >> 4, hh = bh & 15;
  const int t = threadIdx.x;
  const int lane = t & 63, w = t >> 6;
  const int lr = lane & 31, h = lane >> 5;

  const __bf16* Qg = Qb + (size_t)bh * T_ * HS_;
  const __bf16* Kg = Kb + (size_t)bh * T_ * HS_;
  const __bf16* Vg = Vt + (size_t)bh * HS_ * T_;

  // staging geometry: thread t stages LDS slot [t*16, t*16+16) of each 8KB tile.
  const int srow = t >> 3;                                   // tile row (tk or d)
  const int scb = ((t & 7) << 4) ^ ((srow & 7) << 4);        // pre-swizzled src col
  const int kxor = (lr & 7) << 4;                            // read-side swizzle

  const float C2 = 0.04508422f;  // log2(e)/32  (fold 1/sqrt(E)=1/32 into exp2)

#pragma unroll 1
  for (int ph = 0; ph < 2; ++ph) {
    const int qt = (ph == 0) ? qp : 7 - qp;
    const int qbase = qt * 256;
    const int NT = (qt + 1) * 4;
    const int tqg = qbase + w * 32 + lr;

    const __bf16* Qrow = Qg + (size_t)(qbase + w * 32 + lr) * 64;
    bf16x8 qf0 = *(const bf16x8*)(Qrow + h * 8);
    bf16x8 qf1 = *(const bf16x8*)(Qrow + 16 + h * 8);
    bf16x8 qf2 = *(const bf16x8*)(Qrow + 32 + h * 8);
    bf16x8 qf3 = *(const bf16x8*)(Qrow + 48 + h * 8);

    f32x16 o0 = {}, o1 = {};
    float m_run = -INFINITY, l_run = 0.f;
    int cur = 0;

    // prologue stage tile 0 -> buf 0
    gload_lds16((const char*)Kg + (size_t)srow * 128 + scb, (char*)&Ks[0][0] + t * 16);
    gload_lds16((const char*)Vg + (size_t)srow * 4096 + scb, (char*)&Vs[0][0] + t * 16);
    __syncthreads();

#pragma unroll 1
    for (int kt = 0; kt < NT; ++kt) {
      const int kbase = kt * 64;
      if (kt + 1 < NT) {  // stage next tile into buf cur^1 (overlaps compute)
        const int nb = cur ^ 1;
        gload_lds16((const char*)Kg + (size_t)(kbase + 64 + srow) * 128 + scb,
                    (char*)&Ks[nb][0] + t * 16);
        gload_lds16((const char*)Vg + (size_t)srow * 4096 + (size_t)(kbase + 64) * 2 + scb,
                    (char*)&Vs[nb][0] + t * 16);
      }
      if (kbase <= qbase + w * 32 + 31) {  // wave participates (causal)
        const char* KsB = (const char*)&Ks[cur][0];
        const char* VsB = (const char*)&Vs[cur][0];

        // --- QK^T (swapped): S^T[tk][tq], A=K rows tk, B=Q rows tq ---
        f32x16 s0 = {}, s1 = {};
#pragma unroll
        for (int ds = 0; ds < 4; ++ds) {
          bf16x8 k0 = *(const bf16x8*)(KsB + ((lr * 128 + ds * 32 + h * 16) ^ kxor));
          bf16x8 k1 = *(const bf16x8*)(KsB + (((lr + 32) * 128 + ds * 32 + h * 16) ^ kxor));
          bf16x8 qd = (ds == 0) ? qf0 : (ds == 1) ? qf1 : (ds == 2) ? qf2 : qf3;
          s0 = mfma32(k0, qd, s0);
          s1 = mfma32(k1, qd, s1);
        }

        // --- causal mask (diagonal tiles only) ---
        if (kbase + 63 > qbase + w * 32) {
#pragma unroll
          for (int r = 0; r < 16; ++r) {
            int tk0 = kbase + (r & 3) + 8 * (r >> 2) + 4 * h;
            if (tk0 > tqg) s0[r] = -INFINITY;
            if (tk0 + 32 > tqg) s1[r] = -INFINITY;
          }
        }

        // --- online softmax: 31 in-lane fmax + 1 shfl; exp2 with folded scale ---
        float mx = s0[0];
#pragma unroll
        for (int r = 1; r < 16; ++r) mx = fmaxf(mx, s0[r]);
#pragma unroll
        for (int r = 0; r < 16; ++r) mx = fmaxf(mx, s1[r]);
        mx = fmaxf(mx, __shfl_xor(mx, 32));
        float mn = fmaxf(m_run, mx);
        float fac = __builtin_amdgcn_exp2f((m_run - mn) * C2);
        float sum = 0.f;
#pragma unroll
        for (int r = 0; r < 16; ++r) {
          s0[r] = __builtin_amdgcn_exp2f((s0[r] - mn) * C2);
          s1[r] = __builtin_amdgcn_exp2f((s1[r] - mn) * C2);
          sum += s0[r] + s1[r];
        }
        sum += __shfl_xor(sum, 32);
        l_run = l_run * fac + sum;
        m_run = mn;
#pragma unroll
        for (int r = 0; r < 16; ++r) { o0[r] *= fac; o1[r] *= fac; }

        // --- P -> bf16 B-frags (cvt_pk + permlane32_swap), PV: D[d][tq] ---
#pragma unroll
        for (int blk = 0; blk < 4; ++blk) {      // 16-tk blocks
          f32x16& sv = (blk < 2) ? s0 : s1;
          const int off = (blk & 1) * 8;
          unsigned u0 = cvt_pk_bf16(sv[off + 0], sv[off + 1]);
          unsigned u1 = cvt_pk_bf16(sv[off + 2], sv[off + 3]);
          unsigned u2 = cvt_pk_bf16(sv[off + 4], sv[off + 5]);
          unsigned u3 = cvt_pk_bf16(sv[off + 6], sv[off + 7]);
          pl32swap(u0, u2);  // u0 = w0, u2 = w2
          pl32swap(u1, u3);  // u1 = w1, u3 = w3
          union { unsigned u[4]; bf16x8 v; } pb;
          pb.u[0] = u0; pb.u[1] = u1; pb.u[2] = u2; pb.u[3] = u3;
          bf16x8 v0 = *(const bf16x8*)(VsB + ((lr * 128 + blk * 32 + h * 16) ^ kxor));
          bf16x8 v1 = *(const bf16x8*)(VsB + (((lr + 32) * 128 + blk * 32 + h * 16) ^ kxor));
          o0 = mfma32(v0, pb.v, o0);
          o1 = mfma32(v1, pb.v, o1);
        }
      }
      __syncthreads();  // staging done + all waves done with buf[cur]
      cur ^= 1;
    }

    // --- epilogue: O[d][tq] regs -> out[b][tq][hh*64+d], float4 per quartet ---
    const float inv_l = 1.0f / l_run;
    float* orow = out + ((size_t)b * T_ + tqg) * E_ + hh * 64;
#pragma unroll
    for (int d0i = 0; d0i < 2; ++d0i) {
#pragma unroll
      for (int qd = 0; qd < 4; ++qd) {
        float4 v;
        const f32x16& ac = d0i ? o1 : o0;
        v.x = ac[qd * 4 + 0] * inv_l;
        v.y = ac[qd * 4 + 1] * inv_l;
        v.z = ac[qd * 4 + 2] * inv_l;
        v.w = ac[qd * 4 + 3] * inv_l;
        *(float4*)(orow + d0i * 32 + qd * 8 + 4 * h) = v;
      }
    }
  }
}

extern "C" void kernel_launch(void* const* d_in, const int* in_sizes, int n_in,
                              void* d_out, int out_size, void* d_ws, size_t ws_size,
                              hipStream_t stream) {
  const float* x = (const float*)d_in[0];
  const float* Wq = (const float*)d_in[1];
  const float* Wk = (const float*)d_in[2];
  const float* Wv = (const float*)d_in[3];
  float* out = (float*)d_out;

  char* ws = (char*)d_ws;
  __bf16* Xb = (__bf16*)ws;                    // 16 MiB
  __bf16* Wt = (__bf16*)(ws + (16u << 20));    //  6 MiB
  __bf16* Qb = (__bf16*)(ws + (22u << 20));    // 16 MiB
  __bf16* Kb = (__bf16*)(ws + (38u << 20));    // 16 MiB
  __bf16* Vt = (__bf16*)(ws + (54u << 20));    // 16 MiB

  cvt_x_kernel<<<8192, 256, 0, stream>>>(x, Xb);
  cvt_w_kernel<<<dim3(16, 16, 3), 256, 0, stream>>>(Wq, Wk, Wv, Wt);
  qkv_gemm_kernel<<<dim3(64, 8, 3), 256, 0, stream>>>(Xb, Wt, Qb, Kb, Vt);
  attn_kernel<<<dim3(256), 512, 0, stream>>>(Qb, Kb, Vt, out);
}